// Round 7
// baseline (596.856 us; speedup 1.0000x reference)
//
#include <hip/hip_runtime.h>
#include <hip/hip_bf16.h>
#include <hip/hip_fp16.h>

#define N_NODES 100000
#define N_EDGES 1000000
#define BN_EPS 1e-5f
#define N_CHUNKS (N_EDGES / 64)

typedef __attribute__((ext_vector_type(8))) short bf16x8;
typedef __attribute__((ext_vector_type(4))) float f32x4;

// ---------------- ws layout (sorted path) ----------------
// A    : [N_NODES][128] bf16 (25.6 MB) @ 0
// meta @ 25.6MB: stats 128f | ss 128f | flag int | cb8[9] int (@ +1088)
// g    : [N_CHUNKS][4mt][4nt][64][4] fp16 (128 MB) @ meta+4096
//        (cnt[100K] + base[100K] overlay the head of g; dead before k2 writes)
// sd   : 1M int2 @ g+128MB  (packed: x = s | (e&0x7FFF)<<17, y = d | (e>>15)<<17)

__device__ __forceinline__ unsigned pk2(float a, float b) {  // 2x bf16 RNE pack
  unsigned ua = __builtin_bit_cast(unsigned, a);
  unsigned ub = __builtin_bit_cast(unsigned, b);
  ua += 0x7fffu + ((ua >> 16) & 1u);
  ub += 0x7fffu + ((ub >> 16) & 1u);
  return (ua >> 16) | (ub & 0xffff0000u);
}

__device__ __forceinline__ bf16x8 pack8(float4 v0, float4 v1) {
  uint4 u = make_uint4(pk2(v0.x, v0.y), pk2(v0.z, v0.w), pk2(v1.x, v1.y), pk2(v1.z, v1.w));
  return __builtin_bit_cast(bf16x8, u);
}

__device__ __forceinline__ bf16x8 frag_relu_add(uint4 a, uint4 d) {
  uint4 r;
  const unsigned* aw = (const unsigned*)&a;
  const unsigned* dw = (const unsigned*)&d;
  unsigned* rw = (unsigned*)&r;
#pragma unroll
  for (int q = 0; q < 4; ++q) {
    const float alo = __builtin_bit_cast(float, aw[q] << 16);
    const float ahi = __builtin_bit_cast(float, aw[q] & 0xffff0000u);
    const float dlo = __builtin_bit_cast(float, dw[q] << 16);
    const float dhi = __builtin_bit_cast(float, dw[q] & 0xffff0000u);
    rw[q] = pk2(fmaxf(alo + dlo, 0.f), fmaxf(ahi + dhi, 0.f));
  }
  return __builtin_bit_cast(bf16x8, r);
}

__device__ __forceinline__ void load_bfr(const float* __restrict__ W_h, int l15, int l4,
                                         bf16x8 bfr[4][2]) {
#pragma unroll
  for (int nt = 0; nt < 4; ++nt)
#pragma unroll
    for (int kk = 0; kk < 2; ++kk) {
      const float* wp = W_h + (16 * nt + l15) * 64 + (kk * 4 + l4) * 8;
      bfr[nt][kk] = pack8(*(const float4*)wp, *(const float4*)(wp + 4));
    }
}

// per-wave in-kernel dtype probe: int64 edges => all high words of first 32 are 0
__device__ __forceinline__ bool probe_is64(const void* edges) {
  const unsigned* eu = (const unsigned*)edges;
  const int lane = threadIdx.x & 63;
  unsigned pw = (lane < 32) ? eu[2 * lane + 1] : 0u;
  return __ballot(pw != 0) == 0;
}

__global__ __launch_bounds__(64) void k_probe(const unsigned* __restrict__ eu,
                                              int* __restrict__ flag) {
  if (threadIdx.x == 0) {
    unsigned acc = 0;
#pragma unroll
    for (int i = 1; i < 64; i += 2) acc |= eu[i];
    *flag = (acc == 0) ? 1 : 0;
  }
}

// ---------------- counting sort by source node ----------------
__global__ __launch_bounds__(256) void k_zero(unsigned* __restrict__ cnt,
                                              float* __restrict__ stats) {
  for (int i = blockIdx.x * 256 + threadIdx.x; i < N_NODES; i += gridDim.x * 256) cnt[i] = 0u;
  if (blockIdx.x == 0 && threadIdx.x < 128) stats[threadIdx.x] = 0.f;
}

__global__ __launch_bounds__(256) void k_hist(const void* __restrict__ edges,
                                              unsigned* __restrict__ cnt) {
  const bool is64 = probe_is64(edges);
  const long long* e64 = (const long long*)edges;
  const int* e32 = (const int*)edges;
  for (int e = blockIdx.x * 256 + threadIdx.x; e < N_EDGES; e += gridDim.x * 256) {
    const int s = is64 ? (int)e64[e] : e32[e];
    atomicAdd(&cnt[s], 1u);
  }
}

// single block: exclusive scan of cnt[100000] -> base; octant chunk bounds -> cb8
__global__ __launch_bounds__(1024) void k_scan(const unsigned* __restrict__ cnt,
                                               unsigned* __restrict__ basev,
                                               int* __restrict__ cb8) {
  __shared__ unsigned part[1024];
  const int t = threadIdx.x;
  const int s0 = t * 98;
  const int s1 = (s0 + 98 < N_NODES) ? s0 + 98 : N_NODES;
  unsigned sum = 0;
  for (int i = s0; i < s1; ++i) sum += cnt[i];
  part[t] = sum;
  __syncthreads();
  for (int off = 1; off < 1024; off <<= 1) {
    unsigned v = (t >= off) ? part[t - off] : 0u;
    __syncthreads();
    part[t] += v;
    __syncthreads();
  }
  unsigned run = part[t] - sum;  // exclusive prefix
  for (int i = s0; i < s1; ++i) { const unsigned c = cnt[i]; basev[i] = run; run += c; }
  __syncthreads();
  if (t < 8) cb8[t] = (int)(basev[t * 12500] >> 6);
  if (t == 8) cb8[8] = N_CHUNKS;
}

__global__ __launch_bounds__(256) void k_scatter(const void* __restrict__ edges,
                                                 unsigned* __restrict__ basev,
                                                 int2* __restrict__ sd) {
  const bool is64 = probe_is64(edges);
  const long long* e64 = (const long long*)edges;
  const int* e32 = (const int*)edges;
  for (int e = blockIdx.x * 256 + threadIdx.x; e < N_EDGES; e += gridDim.x * 256) {
    int s, d;
    if (is64) { s = (int)e64[e]; d = (int)e64[N_EDGES + e]; }
    else      { s = e32[e];      d = e32[N_EDGES + e]; }
    const unsigned pos = atomicAdd(&basev[s], 1u);
    int2 p;
    p.x = s | ((e & 0x7FFF) << 17);
    p.y = d | ((e >> 15) << 17);
    sd[pos] = p;
  }
}

// K1: A = x @ Wcat^T via swapped-operand MFMA (C^T = Wcat . x^T), no LDS.
__global__ __launch_bounds__(256) void k1_mfma(
    const float* __restrict__ x, const float* __restrict__ W_in,
    const float* __restrict__ b_in, __hip_bfloat16* __restrict__ A,
    float* __restrict__ stats) {
  const int t = threadIdx.x;
  if (blockIdx.x == 0 && t < 128) stats[t] = 0.f;
  const int lane = t & 63;
  const int w = t >> 6;
  const int l15 = lane & 15, l4 = lane >> 4;
  const int nb = blockIdx.x * 128 + (w >> 1) * 64;
  const int cb = (w & 1) * 64;

  bf16x8 wfrag[4][4];
#pragma unroll
  for (int ct = 0; ct < 4; ++ct) {
#pragma unroll
    for (int kk = 0; kk < 4; ++kk) {
      const float* wp = W_in + (16 * ct + l15) * 256 + (cb ? 128 : 0) + 32 * kk + 8 * l4;
      wfrag[ct][kk] = pack8(*(const float4*)wp, *(const float4*)(wp + 4));
    }
  }
  f32x4 acc[4][4];
#pragma unroll
  for (int nt = 0; nt < 4; ++nt)
#pragma unroll
    for (int ct = 0; ct < 4; ++ct)
      acc[nt][ct] = (f32x4){0.f, 0.f, 0.f, 0.f};

#pragma unroll
  for (int nt = 0; nt < 4; ++nt) {
    int node = nb + 16 * nt + l15;
    node = node < N_NODES ? node : N_NODES - 1;
    const float* xr = x + (size_t)node * 128 + 8 * l4;
#pragma unroll
    for (int kk = 0; kk < 4; ++kk) {
      const bf16x8 xf = pack8(*(const float4*)(xr + 32 * kk), *(const float4*)(xr + 32 * kk + 4));
#pragma unroll
      for (int ct = 0; ct < 4; ++ct)
        acc[nt][ct] = __builtin_amdgcn_mfma_f32_16x16x32_bf16(wfrag[ct][kk], xf, acc[nt][ct], 0, 0, 0);
    }
  }

  float4 bv[4];
#pragma unroll
  for (int ct = 0; ct < 4; ++ct)
    bv[ct] = cb ? make_float4(0.f, 0.f, 0.f, 0.f) : *(const float4*)(b_in + 16 * ct + 4 * l4);
#pragma unroll
  for (int nt = 0; nt < 4; ++nt) {
    const int node = nb + 16 * nt + l15;
    if (node < N_NODES) {
      __hip_bfloat16* ap = A + (size_t)node * 128 + cb + 4 * l4;
#pragma unroll
      for (int ct = 0; ct < 4; ++ct) {
        uint2 u;
        u.x = pk2(acc[nt][ct][0] + bv[ct].x, acc[nt][ct][1] + bv[ct].y);
        u.y = pk2(acc[nt][ct][2] + bv[ct].z, acc[nt][ct][3] + bv[ct].w);
        *(uint2*)(ap + 16 * ct) = u;
      }
    }
  }
}

// K2s: sorted-stream BN stats. XCD xb owns octant chunk range [cb8[xb],cb8[xb+1]):
// As rows L1/L2-resident + line-merged (sorted s); Ad random. 2-deep chunk
// pipeline; g spilled tile-native with NT stores.
__global__ __launch_bounds__(256, 2) void k2s_stats(
    const __hip_bfloat16* __restrict__ A, const int2* __restrict__ sd,
    const int* __restrict__ cb8, const float* __restrict__ W_h,
    float* __restrict__ stats, __half* __restrict__ g) {
  const int lane = threadIdx.x & 63;
  const int l15 = lane & 15, l4 = lane >> 4;
  bf16x8 bfr[4][2];
  load_bfr(W_h, l15, l4, bfr);

  const int xb = blockIdx.x & 7;
  const int start = cb8[xb], end = cb8[xb + 1];
  const int gw = (blockIdx.x >> 3) * 4 + (threadIdx.x >> 6);
  const int nw = (gridDim.x >> 3) * 4;
  float vs[4] = {0.f, 0.f, 0.f, 0.f};
  float vq[4] = {0.f, 0.f, 0.f, 0.f};

  for (int i = start + gw; i < end; i += 2 * nw) {
    const int c = i;
    const int cy = i + nw;
    const bool has2 = cy < end;
    // ---- all index loads ----
    int sX[4], dX[4], sY[4], dY[4];
#pragma unroll
    for (int mt = 0; mt < 4; ++mt) {
      const int2 p = sd[c * 64 + mt * 16 + l15];
      sX[mt] = p.x & 0x1FFFF; dX[mt] = p.y & 0x1FFFF;
    }
    const int cyc = has2 ? cy : c;
#pragma unroll
    for (int mt = 0; mt < 4; ++mt) {
      const int2 p = sd[cyc * 64 + mt * 16 + l15];
      sY[mt] = p.x & 0x1FFFF; dY[mt] = p.y & 0x1FFFF;
    }
    // ---- all gathers ----
    uint4 xs0[4], xs1[4], xd0[4], xd1[4];
    uint4 ys0[4], ys1[4], yd0[4], yd1[4];
#pragma unroll
    for (int mt = 0; mt < 4; ++mt) {
      const uint4* As = (const uint4*)(A + (size_t)sX[mt] * 128);
      const uint4* Ad = (const uint4*)(A + (size_t)dX[mt] * 128 + 64);
      xs0[mt] = As[l4]; xs1[mt] = As[4 + l4];
      xd0[mt] = Ad[l4]; xd1[mt] = Ad[4 + l4];
    }
#pragma unroll
    for (int mt = 0; mt < 4; ++mt) {
      const uint4* As = (const uint4*)(A + (size_t)sY[mt] * 128);
      const uint4* Ad = (const uint4*)(A + (size_t)dY[mt] * 128 + 64);
      ys0[mt] = As[l4]; ys1[mt] = As[4 + l4];
      yd0[mt] = Ad[l4]; yd1[mt] = Ad[4 + l4];
    }
    // ---- compute X ----
#pragma unroll
    for (int mt = 0; mt < 4; ++mt) {
      const bf16x8 a0 = frag_relu_add(xs0[mt], xd0[mt]);
      const bf16x8 a1 = frag_relu_add(xs1[mt], xd1[mt]);
#pragma unroll
      for (int nt = 0; nt < 4; ++nt) {
        f32x4 cc = {0.f, 0.f, 0.f, 0.f};
        cc = __builtin_amdgcn_mfma_f32_16x16x32_bf16(a0, bfr[nt][0], cc, 0, 0, 0);
        cc = __builtin_amdgcn_mfma_f32_16x16x32_bf16(a1, bfr[nt][1], cc, 0, 0, 0);
        uint2 u;
        u.x = __builtin_bit_cast(unsigned, __floats2half2_rn(cc[0], cc[1]));
        u.y = __builtin_bit_cast(unsigned, __floats2half2_rn(cc[2], cc[3]));
        __builtin_nontemporal_store(*(unsigned long long*)&u,
            (unsigned long long*)(g + ((((size_t)c * 4 + mt) * 4 + nt) * 64 + lane) * 4));
#pragma unroll
        for (int j = 0; j < 4; ++j) { vs[nt] += cc[j]; vq[nt] += cc[j] * cc[j]; }
      }
    }
    // ---- compute Y ----
    if (has2) {
#pragma unroll
      for (int mt = 0; mt < 4; ++mt) {
        const bf16x8 a0 = frag_relu_add(ys0[mt], yd0[mt]);
        const bf16x8 a1 = frag_relu_add(ys1[mt], yd1[mt]);
#pragma unroll
        for (int nt = 0; nt < 4; ++nt) {
          f32x4 cc = {0.f, 0.f, 0.f, 0.f};
          cc = __builtin_amdgcn_mfma_f32_16x16x32_bf16(a0, bfr[nt][0], cc, 0, 0, 0);
          cc = __builtin_amdgcn_mfma_f32_16x16x32_bf16(a1, bfr[nt][1], cc, 0, 0, 0);
          uint2 u;
          u.x = __builtin_bit_cast(unsigned, __floats2half2_rn(cc[0], cc[1]));
          u.y = __builtin_bit_cast(unsigned, __floats2half2_rn(cc[2], cc[3]));
          __builtin_nontemporal_store(*(unsigned long long*)&u,
              (unsigned long long*)(g + ((((size_t)cy * 4 + mt) * 4 + nt) * 64 + lane) * 4));
#pragma unroll
          for (int j = 0; j < 4; ++j) { vs[nt] += cc[j]; vq[nt] += cc[j] * cc[j]; }
        }
      }
    }
  }
#pragma unroll
  for (int nt = 0; nt < 4; ++nt) {
    float s1 = vs[nt], s2 = vq[nt];
    s1 += __shfl_xor(s1, 16, 64); s1 += __shfl_xor(s1, 32, 64);
    s2 += __shfl_xor(s2, 16, 64); s2 += __shfl_xor(s2, 32, 64);
    if (lane < 16) {
      atomicAdd(&stats[lane + 16 * nt], s1);
      atomicAdd(&stats[64 + lane + 16 * nt], s2);
    }
  }
}

// K3: fold BN into per-channel scale/shift (b_h cancels exactly).
__global__ __launch_bounds__(64) void k3_finalize(
    const float* __restrict__ stats, const float* __restrict__ gamma,
    const float* __restrict__ beta, float* __restrict__ ss) {
  const int c = threadIdx.x;
  if (c < 64) {
    const float inv_e = 1.f / (float)N_EDGES;
    const float mg = stats[c] * inv_e;
    const float var = stats[64 + c] * inv_e - mg * mg;
    const float scale = gamma[c] * rsqrtf(var + BN_EPS);
    ss[c] = scale;
    ss[64 + c] = beta[c] - scale * mg;
  }
}

// K4s: stream g (NT), finish, scatter out[orig_e] (e unpacked from sd).
__global__ __launch_bounds__(256) void k4s_out(
    const __half* __restrict__ g, const int2* __restrict__ sd,
    const float* __restrict__ ss, const float* __restrict__ W_out,
    const float* __restrict__ b_out, float* __restrict__ out) {
  const int lane = threadIdx.x & 63;
  const int l15 = lane & 15, l4 = lane >> 4;
  float scl[4], shf[4], wo[4];
#pragma unroll
  for (int nt = 0; nt < 4; ++nt) {
    scl[nt] = ss[l15 + 16 * nt];
    shf[nt] = ss[64 + l15 + 16 * nt];
    wo[nt] = W_out[l15 + 16 * nt];
  }
  const float bo = b_out[0];
  const int gwave = blockIdx.x * 4 + (threadIdx.x >> 6);
  const int nwaves = gridDim.x * 4;
  for (int chunk = gwave; chunk < N_CHUNKS; chunk += nwaves) {
#pragma unroll
    for (int mt = 0; mt < 4; ++mt) {
      float t0 = 0.f, t1 = 0.f, t2 = 0.f, t3 = 0.f;
#pragma unroll
      for (int nt = 0; nt < 4; ++nt) {
        const unsigned long long uv = __builtin_nontemporal_load(
            (const unsigned long long*)(g + ((((size_t)chunk * 4 + mt) * 4 + nt) * 64 + lane) * 4));
        const __half2 h0 = __builtin_bit_cast(__half2, (unsigned)(uv & 0xffffffffu));
        const __half2 h1 = __builtin_bit_cast(__half2, (unsigned)(uv >> 32));
        t0 += fmaxf(fmaf(__low2float(h0),  scl[nt], shf[nt]), 0.f) * wo[nt];
        t1 += fmaxf(fmaf(__high2float(h0), scl[nt], shf[nt]), 0.f) * wo[nt];
        t2 += fmaxf(fmaf(__low2float(h1),  scl[nt], shf[nt]), 0.f) * wo[nt];
        t3 += fmaxf(fmaf(__high2float(h1), scl[nt], shf[nt]), 0.f) * wo[nt];
      }
      float rr[4];
#pragma unroll
      for (int j = 0; j < 4; ++j) {
        float r = (j == 0) ? t0 : (j == 1) ? t1 : (j == 2) ? t2 : t3;
        r += __shfl_xor(r, 1, 64);
        r += __shfl_xor(r, 2, 64);
        r += __shfl_xor(r, 4, 64);
        r += __shfl_xor(r, 8, 64);
        rr[j] = r + bo;
      }
      if (l15 == 0) {
        const int ebase = chunk * 64 + mt * 16 + 4 * l4;
#pragma unroll
        for (int j = 0; j < 4; ++j) {
          const int2 p = sd[ebase + j];
          const int e = (int)(((unsigned)p.x >> 17) | (((unsigned)p.y >> 17) << 15));
          out[e] = rr[j];
        }
      }
    }
  }
}

// ---------------- fallback path (unsorted, R6) ----------------
template<bool STORE_G>
__global__ __launch_bounds__(256, 2) void k2_stats(
    const __hip_bfloat16* __restrict__ A, const void* __restrict__ edges,
    const int* __restrict__ flag, const float* __restrict__ W_h,
    float* __restrict__ stats, __half* __restrict__ g) {
  const int lane = threadIdx.x & 63;
  const int l15 = lane & 15, l4 = lane >> 4;
  bf16x8 bfr[4][2];
  load_bfr(W_h, l15, l4, bfr);
  const int is64 = *flag;
  const long long* e64 = (const long long*)edges;
  const int* e32 = (const int*)edges;
  float vs[4] = {0.f, 0.f, 0.f, 0.f};
  float vq[4] = {0.f, 0.f, 0.f, 0.f};
  const int gwave = blockIdx.x * 4 + (threadIdx.x >> 6);
  const int nwaves = gridDim.x * 4;
  for (int c = gwave; c < N_CHUNKS; c += 2 * nwaves) {
    const int cy = c + nwaves;
    const bool has2 = cy < N_CHUNKS;
    int sX[4], dX[4], sY[4], dY[4];
#pragma unroll
    for (int mt = 0; mt < 4; ++mt) {
      const int ex = c * 64 + mt * 16 + l15;
      if (is64) { sX[mt] = (int)e64[ex]; dX[mt] = (int)e64[N_EDGES + ex]; }
      else      { sX[mt] = e32[ex];      dX[mt] = e32[N_EDGES + ex]; }
    }
    const int cyc = has2 ? cy : c;
#pragma unroll
    for (int mt = 0; mt < 4; ++mt) {
      const int ey = cyc * 64 + mt * 16 + l15;
      if (is64) { sY[mt] = (int)e64[ey]; dY[mt] = (int)e64[N_EDGES + ey]; }
      else      { sY[mt] = e32[ey];      dY[mt] = e32[N_EDGES + ey]; }
    }
    uint4 xs0[4], xs1[4], xd0[4], xd1[4];
    uint4 ys0[4], ys1[4], yd0[4], yd1[4];
#pragma unroll
    for (int mt = 0; mt < 4; ++mt) {
      const uint4* As = (const uint4*)(A + (size_t)sX[mt] * 128);
      const uint4* Ad = (const uint4*)(A + (size_t)dX[mt] * 128 + 64);
      xs0[mt] = As[l4]; xs1[mt] = As[4 + l4];
      xd0[mt] = Ad[l4]; xd1[mt] = Ad[4 + l4];
    }
#pragma unroll
    for (int mt = 0; mt < 4; ++mt) {
      const uint4* As = (const uint4*)(A + (size_t)sY[mt] * 128);
      const uint4* Ad = (const uint4*)(A + (size_t)dY[mt] * 128 + 64);
      ys0[mt] = As[l4]; ys1[mt] = As[4 + l4];
      yd0[mt] = Ad[l4]; yd1[mt] = Ad[4 + l4];
    }
#pragma unroll
    for (int mt = 0; mt < 4; ++mt) {
      const bf16x8 a0 = frag_relu_add(xs0[mt], xd0[mt]);
      const bf16x8 a1 = frag_relu_add(xs1[mt], xd1[mt]);
#pragma unroll
      for (int nt = 0; nt < 4; ++nt) {
        f32x4 cc = {0.f, 0.f, 0.f, 0.f};
        cc = __builtin_amdgcn_mfma_f32_16x16x32_bf16(a0, bfr[nt][0], cc, 0, 0, 0);
        cc = __builtin_amdgcn_mfma_f32_16x16x32_bf16(a1, bfr[nt][1], cc, 0, 0, 0);
        if (STORE_G) {
          uint2 u;
          u.x = __builtin_bit_cast(unsigned, __floats2half2_rn(cc[0], cc[1]));
          u.y = __builtin_bit_cast(unsigned, __floats2half2_rn(cc[2], cc[3]));
          *(uint2*)(g + ((((size_t)c * 4 + mt) * 4 + nt) * 64 + lane) * 4) = u;
        }
#pragma unroll
        for (int j = 0; j < 4; ++j) { vs[nt] += cc[j]; vq[nt] += cc[j] * cc[j]; }
      }
    }
    if (has2) {
#pragma unroll
      for (int mt = 0; mt < 4; ++mt) {
        const bf16x8 a0 = frag_relu_add(ys0[mt], yd0[mt]);
        const bf16x8 a1 = frag_relu_add(ys1[mt], yd1[mt]);
#pragma unroll
        for (int nt = 0; nt < 4; ++nt) {
          f32x4 cc = {0.f, 0.f, 0.f, 0.f};
          cc = __builtin_amdgcn_mfma_f32_16x16x32_bf16(a0, bfr[nt][0], cc, 0, 0, 0);
          cc = __builtin_amdgcn_mfma_f32_16x16x32_bf16(a1, bfr[nt][1], cc, 0, 0, 0);
          if (STORE_G) {
            uint2 u;
            u.x = __builtin_bit_cast(unsigned, __floats2half2_rn(cc[0], cc[1]));
            u.y = __builtin_bit_cast(unsigned, __floats2half2_rn(cc[2], cc[3]));
            *(uint2*)(g + ((((size_t)cy * 4 + mt) * 4 + nt) * 64 + lane) * 4) = u;
          }
#pragma unroll
          for (int j = 0; j < 4; ++j) { vs[nt] += cc[j]; vq[nt] += cc[j] * cc[j]; }
        }
      }
    }
  }
#pragma unroll
  for (int nt = 0; nt < 4; ++nt) {
    float s1 = vs[nt], s2 = vq[nt];
    s1 += __shfl_xor(s1, 16, 64); s1 += __shfl_xor(s1, 32, 64);
    s2 += __shfl_xor(s2, 16, 64); s2 += __shfl_xor(s2, 32, 64);
    if (lane < 16) {
      atomicAdd(&stats[lane + 16 * nt], s1);
      atomicAdd(&stats[64 + lane + 16 * nt], s2);
    }
  }
}

__global__ __launch_bounds__(256) void k4_stream(
    const __half* __restrict__ g, const float* __restrict__ ss,
    const float* __restrict__ W_out, const float* __restrict__ b_out,
    float* __restrict__ out) {
  const int lane = threadIdx.x & 63;
  const int l15 = lane & 15, l4 = lane >> 4;
  float scl[4], shf[4], wo[4];
#pragma unroll
  for (int nt = 0; nt < 4; ++nt) {
    scl[nt] = ss[l15 + 16 * nt];
    shf[nt] = ss[64 + l15 + 16 * nt];
    wo[nt] = W_out[l15 + 16 * nt];
  }
  const float bo = b_out[0];
  const int gwave = blockIdx.x * 4 + (threadIdx.x >> 6);
  const int nwaves = gridDim.x * 4;
  for (int chunk = gwave; chunk < N_CHUNKS; chunk += nwaves) {
#pragma unroll
    for (int mt = 0; mt < 4; ++mt) {
      float t0 = 0.f, t1 = 0.f, t2 = 0.f, t3 = 0.f;
#pragma unroll
      for (int nt = 0; nt < 4; ++nt) {
        const uint2 u = *(const uint2*)(g + ((((size_t)chunk * 4 + mt) * 4 + nt) * 64 + lane) * 4);
        const __half2 h0 = __builtin_bit_cast(__half2, u.x);
        const __half2 h1 = __builtin_bit_cast(__half2, u.y);
        t0 += fmaxf(fmaf(__low2float(h0),  scl[nt], shf[nt]), 0.f) * wo[nt];
        t1 += fmaxf(fmaf(__high2float(h0), scl[nt], shf[nt]), 0.f) * wo[nt];
        t2 += fmaxf(fmaf(__low2float(h1),  scl[nt], shf[nt]), 0.f) * wo[nt];
        t3 += fmaxf(fmaf(__high2float(h1), scl[nt], shf[nt]), 0.f) * wo[nt];
      }
      const int ebase = chunk * 64 + mt * 16 + 4 * l4;
#pragma unroll
      for (int j = 0; j < 4; ++j) {
        float r = (j == 0) ? t0 : (j == 1) ? t1 : (j == 2) ? t2 : t3;
        r += __shfl_xor(r, 1, 64);
        r += __shfl_xor(r, 2, 64);
        r += __shfl_xor(r, 4, 64);
        r += __shfl_xor(r, 8, 64);
        if (l15 == 0) out[ebase + j] = r + bo;
      }
    }
  }
}

__global__ __launch_bounds__(256) void k4_gather(
    const __hip_bfloat16* __restrict__ A, const void* __restrict__ edges,
    const int* __restrict__ flag, const float* __restrict__ W_h,
    const float* __restrict__ ss, const float* __restrict__ W_out,
    const float* __restrict__ b_out, float* __restrict__ out) {
  const int lane = threadIdx.x & 63;
  const int l15 = lane & 15, l4 = lane >> 4;
  bf16x8 bfr[4][2];
  load_bfr(W_h, l15, l4, bfr);
  float scl[4], shf[4], wo[4];
#pragma unroll
  for (int nt = 0; nt < 4; ++nt) {
    scl[nt] = ss[l15 + 16 * nt];
    shf[nt] = ss[64 + l15 + 16 * nt];
    wo[nt] = W_out[l15 + 16 * nt];
  }
  const float bo = b_out[0];
  const int is64 = *flag;
  const long long* e64 = (const long long*)edges;
  const int* e32 = (const int*)edges;
  const int gwave = blockIdx.x * 4 + (threadIdx.x >> 6);
  const int nwaves = gridDim.x * 4;
  for (int chunk = gwave; chunk < N_CHUNKS; chunk += nwaves) {
    const int base = chunk * 64;
#pragma unroll
    for (int mt = 0; mt < 4; ++mt) {
      const int eidx = base + mt * 16 + l15;
      int s, d;
      if (is64) { s = (int)e64[eidx]; d = (int)e64[N_EDGES + eidx]; }
      else      { s = e32[eidx];      d = e32[N_EDGES + eidx]; }
      const uint4* As = (const uint4*)(A + (size_t)s * 128);
      const uint4* Ad = (const uint4*)(A + (size_t)d * 128 + 64);
      const bf16x8 a0 = frag_relu_add(As[l4], Ad[l4]);
      const bf16x8 a1 = frag_relu_add(As[4 + l4], Ad[4 + l4]);
      float t0 = 0.f, t1 = 0.f, t2 = 0.f, t3 = 0.f;
#pragma unroll
      for (int nt = 0; nt < 4; ++nt) {
        f32x4 cc = {0.f, 0.f, 0.f, 0.f};
        cc = __builtin_amdgcn_mfma_f32_16x16x32_bf16(a0, bfr[nt][0], cc, 0, 0, 0);
        cc = __builtin_amdgcn_mfma_f32_16x16x32_bf16(a1, bfr[nt][1], cc, 0, 0, 0);
        t0 += fmaxf(fmaf(cc[0], scl[nt], shf[nt]), 0.f) * wo[nt];
        t1 += fmaxf(fmaf(cc[1], scl[nt], shf[nt]), 0.f) * wo[nt];
        t2 += fmaxf(fmaf(cc[2], scl[nt], shf[nt]), 0.f) * wo[nt];
        t3 += fmaxf(fmaf(cc[3], scl[nt], shf[nt]), 0.f) * wo[nt];
      }
      const int ebase = base + mt * 16 + 4 * l4;
#pragma unroll
      for (int j = 0; j < 4; ++j) {
        float r = (j == 0) ? t0 : (j == 1) ? t1 : (j == 2) ? t2 : t3;
        r += __shfl_xor(r, 1, 64);
        r += __shfl_xor(r, 2, 64);
        r += __shfl_xor(r, 4, 64);
        r += __shfl_xor(r, 8, 64);
        if (l15 == 0) out[ebase + j] = r + bo;
      }
    }
  }
}

extern "C" void kernel_launch(void* const* d_in, const int* in_sizes, int n_in,
                              void* d_out, int out_size, void* d_ws, size_t ws_size,
                              hipStream_t stream) {
  const float* x     = (const float*)d_in[0];
  const void*  edges = d_in[1];
  const float* W_in  = (const float*)d_in[2];
  const float* b_in  = (const float*)d_in[3];
  const float* W_h   = (const float*)d_in[4];
  const float* gamma = (const float*)d_in[6];
  const float* beta  = (const float*)d_in[7];
  const float* W_out = (const float*)d_in[8];
  const float* b_out = (const float*)d_in[9];
  float* out = (float*)d_out;

  char* base = (char*)d_ws;
  __hip_bfloat16* A = (__hip_bfloat16*)base;
  const size_t offMeta = (size_t)N_NODES * 128 * sizeof(__hip_bfloat16);  // 25.6 MB
  float* stats = (float*)(base + offMeta);
  float* ss    = stats + 128;
  int*   flag  = (int*)(base + offMeta + 1024);
  int*   cb8   = (int*)(base + offMeta + 1088);
  const size_t offG = offMeta + 4096;
  __half* g = (__half*)(base + offG);
  unsigned* cnt   = (unsigned*)(base + offG);            // overlays g head; dead before k2
  unsigned* basev = cnt + N_NODES;
  const size_t offSd = offG + (size_t)N_EDGES * 64 * sizeof(__half);  // +128 MB
  int2* sd = (int2*)(base + offSd);
  const size_t needSorted = offSd + (size_t)N_EDGES * sizeof(int2);
  const size_t needG = offSd;  // unsorted path: A + meta + g

  if (ws_size >= needSorted) {
    k_zero<<<128, 256, 0, stream>>>(cnt, stats);
    k_hist<<<512, 256, 0, stream>>>(edges, cnt);
    k_scan<<<1, 1024, 0, stream>>>(cnt, basev, cb8);
    k_scatter<<<512, 256, 0, stream>>>(edges, basev, sd);
    k1_mfma<<<782, 256, 0, stream>>>(x, W_in, b_in, A, stats);
    k2s_stats<<<2048, 256, 0, stream>>>(A, sd, cb8, W_h, stats, g);
    k3_finalize<<<1, 64, 0, stream>>>(stats, gamma, beta, ss);
    k4s_out<<<2048, 256, 0, stream>>>(g, sd, ss, W_out, b_out, out);
  } else if (ws_size >= needG) {
    k_probe<<<1, 64, 0, stream>>>((const unsigned*)edges, flag);
    k1_mfma<<<782, 256, 0, stream>>>(x, W_in, b_in, A, stats);
    k2_stats<true><<<976, 256, 0, stream>>>(A, edges, flag, W_h, stats, g);
    k3_finalize<<<1, 64, 0, stream>>>(stats, gamma, beta, ss);
    k4_stream<<<1024, 256, 0, stream>>>(g, ss, W_out, b_out, out);
  } else {
    k_probe<<<1, 64, 0, stream>>>((const unsigned*)edges, flag);
    k1_mfma<<<782, 256, 0, stream>>>(x, W_in, b_in, A, stats);
    k2_stats<false><<<976, 256, 0, stream>>>(A, edges, flag, W_h, stats, g);
    k3_finalize<<<1, 64, 0, stream>>>(stats, gamma, beta, ss);
    k4_gather<<<1024, 256, 0, stream>>>(A, edges, flag, W_h, ss, W_out, b_out, out);
  }
}

// Round 8
// 197.453 us; speedup vs baseline: 3.0228x; 3.0228x over previous
//
#include <hip/hip_runtime.h>
#include <hip/hip_bf16.h>
#include <hip/hip_fp16.h>

#define N_NODES 100000
#define N_EDGES 1000000
#define BN_EPS 1e-5f
#define N_CHUNKS (N_EDGES / 64)

typedef __attribute__((ext_vector_type(8))) short bf16x8;
typedef __attribute__((ext_vector_type(4))) float f32x4;

// ---------------- ws layout ----------------
// A     : [N_NODES][128] bf16 (25.6 MB) @ 0
// meta  @ 25.6MB: stats 128f | ss 128f | flag int
// g     : [N_CHUNKS][4mt][4nt][64][4] fp16 (128 MB) @ meta+4096 (if ws allows)

__device__ __forceinline__ unsigned pk2(float a, float b) {  // 2x bf16 RNE pack
  unsigned ua = __builtin_bit_cast(unsigned, a);
  unsigned ub = __builtin_bit_cast(unsigned, b);
  ua += 0x7fffu + ((ua >> 16) & 1u);
  ub += 0x7fffu + ((ub >> 16) & 1u);
  return (ua >> 16) | (ub & 0xffff0000u);
}

__device__ __forceinline__ bf16x8 pack8(float4 v0, float4 v1) {
  uint4 u = make_uint4(pk2(v0.x, v0.y), pk2(v0.z, v0.w), pk2(v1.x, v1.y), pk2(v1.z, v1.w));
  return __builtin_bit_cast(bf16x8, u);
}

__device__ __forceinline__ bf16x8 frag_relu_add(uint4 a, uint4 d) {
  uint4 r;
  const unsigned* aw = (const unsigned*)&a;
  const unsigned* dw = (const unsigned*)&d;
  unsigned* rw = (unsigned*)&r;
#pragma unroll
  for (int q = 0; q < 4; ++q) {
    const float alo = __builtin_bit_cast(float, aw[q] << 16);
    const float ahi = __builtin_bit_cast(float, aw[q] & 0xffff0000u);
    const float dlo = __builtin_bit_cast(float, dw[q] << 16);
    const float dhi = __builtin_bit_cast(float, dw[q] & 0xffff0000u);
    rw[q] = pk2(fmaxf(alo + dlo, 0.f), fmaxf(ahi + dhi, 0.f));
  }
  return __builtin_bit_cast(bf16x8, r);
}

__device__ __forceinline__ void load_bfr(const float* __restrict__ W_h, int l15, int l4,
                                         bf16x8 bfr[4][2]) {
#pragma unroll
  for (int nt = 0; nt < 4; ++nt)
#pragma unroll
    for (int kk = 0; kk < 2; ++kk) {
      const float* wp = W_h + (16 * nt + l15) * 64 + (kk * 4 + l4) * 8;
      bfr[nt][kk] = pack8(*(const float4*)wp, *(const float4*)(wp + 4));
    }
}

// K1: A = x @ Wcat^T via swapped-operand MFMA (C^T = Wcat . x^T), no LDS.
// Block 0 additionally zeroes stats and probes the edge dtype (int64 -> all
// high words of the first 32 entries are 0).
__global__ __launch_bounds__(256) void k1_mfma(
    const float* __restrict__ x, const float* __restrict__ W_in,
    const float* __restrict__ b_in, const unsigned* __restrict__ edges_u,
    __hip_bfloat16* __restrict__ A, float* __restrict__ stats,
    int* __restrict__ flag) {
  const int t = threadIdx.x;
  if (blockIdx.x == 0) {
    if (t < 128) stats[t] = 0.f;
    if (t < 64) {
      const unsigned pw = (t < 32) ? edges_u[2 * t + 1] : 0u;
      const unsigned long long m = __ballot(pw != 0);
      if (t == 0) *flag = (m == 0) ? 1 : 0;
    }
  }
  const int lane = t & 63;
  const int w = t >> 6;
  const int l15 = lane & 15, l4 = lane >> 4;
  const int nb = blockIdx.x * 128 + (w >> 1) * 64;
  const int cb = (w & 1) * 64;

  bf16x8 wfrag[4][4];
#pragma unroll
  for (int ct = 0; ct < 4; ++ct) {
#pragma unroll
    for (int kk = 0; kk < 4; ++kk) {
      const float* wp = W_in + (16 * ct + l15) * 256 + (cb ? 128 : 0) + 32 * kk + 8 * l4;
      wfrag[ct][kk] = pack8(*(const float4*)wp, *(const float4*)(wp + 4));
    }
  }
  f32x4 acc[4][4];
#pragma unroll
  for (int nt = 0; nt < 4; ++nt)
#pragma unroll
    for (int ct = 0; ct < 4; ++ct)
      acc[nt][ct] = (f32x4){0.f, 0.f, 0.f, 0.f};

#pragma unroll
  for (int nt = 0; nt < 4; ++nt) {
    int node = nb + 16 * nt + l15;
    node = node < N_NODES ? node : N_NODES - 1;
    const float* xr = x + (size_t)node * 128 + 8 * l4;
#pragma unroll
    for (int kk = 0; kk < 4; ++kk) {
      const bf16x8 xf = pack8(*(const float4*)(xr + 32 * kk), *(const float4*)(xr + 32 * kk + 4));
#pragma unroll
      for (int ct = 0; ct < 4; ++ct)
        acc[nt][ct] = __builtin_amdgcn_mfma_f32_16x16x32_bf16(wfrag[ct][kk], xf, acc[nt][ct], 0, 0, 0);
    }
  }

  float4 bv[4];
#pragma unroll
  for (int ct = 0; ct < 4; ++ct)
    bv[ct] = cb ? make_float4(0.f, 0.f, 0.f, 0.f) : *(const float4*)(b_in + 16 * ct + 4 * l4);
#pragma unroll
  for (int nt = 0; nt < 4; ++nt) {
    const int node = nb + 16 * nt + l15;
    if (node < N_NODES) {
      __hip_bfloat16* ap = A + (size_t)node * 128 + cb + 4 * l4;
#pragma unroll
      for (int ct = 0; ct < 4; ++ct) {
        uint2 u;
        u.x = pk2(acc[nt][ct][0] + bv[ct].x, acc[nt][ct][1] + bv[ct].y);
        u.y = pk2(acc[nt][ct][2] + bv[ct].z, acc[nt][ct][3] + bv[ct].w);
        *(uint2*)(ap + 16 * ct) = u;
      }
    }
  }
}

// K2: BN stats over g = h1 @ W_h^T, 2-deep chunk pipeline: all loads of both
// chunks issued before any compute; sched_barrier pins issue order so the
// compiler cannot sink Y's gathers below X's compute. Regular (L2) g stores.
template<bool STORE_G>
__global__ __launch_bounds__(256, 2) void k2_stats(
    const __hip_bfloat16* __restrict__ A, const void* __restrict__ edges,
    const int* __restrict__ flag, const float* __restrict__ W_h,
    float* __restrict__ stats, __half* __restrict__ g) {
  const int lane = threadIdx.x & 63;
  const int l15 = lane & 15, l4 = lane >> 4;
  bf16x8 bfr[4][2];
  load_bfr(W_h, l15, l4, bfr);

  const int is64 = *flag;
  const long long* e64 = (const long long*)edges;
  const int* e32 = (const int*)edges;
  float vs[4] = {0.f, 0.f, 0.f, 0.f};
  float vq[4] = {0.f, 0.f, 0.f, 0.f};
  const int gwave = blockIdx.x * 4 + (threadIdx.x >> 6);
  const int nwaves = gridDim.x * 4;

  for (int c = gwave; c < N_CHUNKS; c += 2 * nwaves) {
    const int cy = c + nwaves;
    const bool has2 = cy < N_CHUNKS;
    // ---- all index loads ----
    int sX[4], dX[4], sY[4], dY[4];
#pragma unroll
    for (int mt = 0; mt < 4; ++mt) {
      const int ex = c * 64 + mt * 16 + l15;
      if (is64) { sX[mt] = (int)e64[ex]; dX[mt] = (int)e64[N_EDGES + ex]; }
      else      { sX[mt] = e32[ex];      dX[mt] = e32[N_EDGES + ex]; }
    }
    const int cyc = has2 ? cy : c;
#pragma unroll
    for (int mt = 0; mt < 4; ++mt) {
      const int ey = cyc * 64 + mt * 16 + l15;
      if (is64) { sY[mt] = (int)e64[ey]; dY[mt] = (int)e64[N_EDGES + ey]; }
      else      { sY[mt] = e32[ey];      dY[mt] = e32[N_EDGES + ey]; }
    }
    // ---- all gathers (X then Y) ----
    uint4 xs0[4], xs1[4], xd0[4], xd1[4];
    uint4 ys0[4], ys1[4], yd0[4], yd1[4];
#pragma unroll
    for (int mt = 0; mt < 4; ++mt) {
      const uint4* As = (const uint4*)(A + (size_t)sX[mt] * 128);
      const uint4* Ad = (const uint4*)(A + (size_t)dX[mt] * 128 + 64);
      xs0[mt] = As[l4]; xs1[mt] = As[4 + l4];
      xd0[mt] = Ad[l4]; xd1[mt] = Ad[4 + l4];
    }
#pragma unroll
    for (int mt = 0; mt < 4; ++mt) {
      const uint4* As = (const uint4*)(A + (size_t)sY[mt] * 128);
      const uint4* Ad = (const uint4*)(A + (size_t)dY[mt] * 128 + 64);
      ys0[mt] = As[l4]; ys1[mt] = As[4 + l4];
      yd0[mt] = Ad[l4]; yd1[mt] = Ad[4 + l4];
    }
    __builtin_amdgcn_sched_barrier(0);  // pin: all 32 gathers issued before compute
    // ---- compute X ----
#pragma unroll
    for (int mt = 0; mt < 4; ++mt) {
      const bf16x8 a0 = frag_relu_add(xs0[mt], xd0[mt]);
      const bf16x8 a1 = frag_relu_add(xs1[mt], xd1[mt]);
#pragma unroll
      for (int nt = 0; nt < 4; ++nt) {
        f32x4 cc = {0.f, 0.f, 0.f, 0.f};
        cc = __builtin_amdgcn_mfma_f32_16x16x32_bf16(a0, bfr[nt][0], cc, 0, 0, 0);
        cc = __builtin_amdgcn_mfma_f32_16x16x32_bf16(a1, bfr[nt][1], cc, 0, 0, 0);
        if (STORE_G) {
          uint2 u;
          u.x = __builtin_bit_cast(unsigned, __floats2half2_rn(cc[0], cc[1]));
          u.y = __builtin_bit_cast(unsigned, __floats2half2_rn(cc[2], cc[3]));
          *(uint2*)(g + ((((size_t)c * 4 + mt) * 4 + nt) * 64 + lane) * 4) = u;
        }
#pragma unroll
        for (int j = 0; j < 4; ++j) { vs[nt] += cc[j]; vq[nt] += cc[j] * cc[j]; }
      }
    }
    // ---- compute Y ----
    if (has2) {
#pragma unroll
      for (int mt = 0; mt < 4; ++mt) {
        const bf16x8 a0 = frag_relu_add(ys0[mt], yd0[mt]);
        const bf16x8 a1 = frag_relu_add(ys1[mt], yd1[mt]);
#pragma unroll
        for (int nt = 0; nt < 4; ++nt) {
          f32x4 cc = {0.f, 0.f, 0.f, 0.f};
          cc = __builtin_amdgcn_mfma_f32_16x16x32_bf16(a0, bfr[nt][0], cc, 0, 0, 0);
          cc = __builtin_amdgcn_mfma_f32_16x16x32_bf16(a1, bfr[nt][1], cc, 0, 0, 0);
          if (STORE_G) {
            uint2 u;
            u.x = __builtin_bit_cast(unsigned, __floats2half2_rn(cc[0], cc[1]));
            u.y = __builtin_bit_cast(unsigned, __floats2half2_rn(cc[2], cc[3]));
            *(uint2*)(g + ((((size_t)cy * 4 + mt) * 4 + nt) * 64 + lane) * 4) = u;
          }
#pragma unroll
          for (int j = 0; j < 4; ++j) { vs[nt] += cc[j]; vq[nt] += cc[j] * cc[j]; }
        }
      }
    }
  }
#pragma unroll
  for (int nt = 0; nt < 4; ++nt) {
    float s1 = vs[nt], s2 = vq[nt];
    s1 += __shfl_xor(s1, 16, 64); s1 += __shfl_xor(s1, 32, 64);
    s2 += __shfl_xor(s2, 16, 64); s2 += __shfl_xor(s2, 32, 64);
    if (lane < 16) {
      atomicAdd(&stats[lane + 16 * nt], s1);
      atomicAdd(&stats[64 + lane + 16 * nt], s2);
    }
  }
}

// K3: fold BN into per-channel scale/shift (b_h cancels exactly).
__global__ __launch_bounds__(64) void k3_finalize(
    const float* __restrict__ stats, const float* __restrict__ gamma,
    const float* __restrict__ beta, float* __restrict__ ss) {
  const int c = threadIdx.x;
  if (c < 64) {
    const float inv_e = 1.f / (float)N_EDGES;
    const float mg = stats[c] * inv_e;
    const float var = stats[64 + c] * inv_e - mg * mg;
    const float scale = gamma[c] * rsqrtf(var + BN_EPS);
    ss[c] = scale;
    ss[64 + c] = beta[c] - scale * mg;
  }
}

// K4a: streaming finish from spilled g (read-once -> NT loads).
__global__ __launch_bounds__(256) void k4_stream(
    const __half* __restrict__ g, const float* __restrict__ ss,
    const float* __restrict__ W_out, const float* __restrict__ b_out,
    float* __restrict__ out) {
  const int lane = threadIdx.x & 63;
  const int l15 = lane & 15, l4 = lane >> 4;
  float scl[4], shf[4], wo[4];
#pragma unroll
  for (int nt = 0; nt < 4; ++nt) {
    scl[nt] = ss[l15 + 16 * nt];
    shf[nt] = ss[64 + l15 + 16 * nt];
    wo[nt] = W_out[l15 + 16 * nt];
  }
  const float bo = b_out[0];
  const int gwave = blockIdx.x * 4 + (threadIdx.x >> 6);
  const int nwaves = gridDim.x * 4;
  for (int chunk = gwave; chunk < N_CHUNKS; chunk += nwaves) {
#pragma unroll
    for (int mt = 0; mt < 4; ++mt) {
      float t0 = 0.f, t1 = 0.f, t2 = 0.f, t3 = 0.f;
#pragma unroll
      for (int nt = 0; nt < 4; ++nt) {
        const unsigned long long uv = __builtin_nontemporal_load(
            (const unsigned long long*)(g + ((((size_t)chunk * 4 + mt) * 4 + nt) * 64 + lane) * 4));
        const __half2 h0 = __builtin_bit_cast(__half2, (unsigned)(uv & 0xffffffffu));
        const __half2 h1 = __builtin_bit_cast(__half2, (unsigned)(uv >> 32));
        t0 += fmaxf(fmaf(__low2float(h0),  scl[nt], shf[nt]), 0.f) * wo[nt];
        t1 += fmaxf(fmaf(__high2float(h0), scl[nt], shf[nt]), 0.f) * wo[nt];
        t2 += fmaxf(fmaf(__low2float(h1),  scl[nt], shf[nt]), 0.f) * wo[nt];
        t3 += fmaxf(fmaf(__high2float(h1), scl[nt], shf[nt]), 0.f) * wo[nt];
      }
      const int ebase = chunk * 64 + mt * 16 + 4 * l4;
#pragma unroll
      for (int j = 0; j < 4; ++j) {
        float r = (j == 0) ? t0 : (j == 1) ? t1 : (j == 2) ? t2 : t3;
        r += __shfl_xor(r, 1, 64);
        r += __shfl_xor(r, 2, 64);
        r += __shfl_xor(r, 4, 64);
        r += __shfl_xor(r, 8, 64);
        if (l15 == 0) out[ebase + j] = r + bo;
      }
    }
  }
}

// K4b: fallback — recompute g by gather+MFMA (LDS-free), then finish.
__global__ __launch_bounds__(256) void k4_gather(
    const __hip_bfloat16* __restrict__ A, const void* __restrict__ edges,
    const int* __restrict__ flag, const float* __restrict__ W_h,
    const float* __restrict__ ss, const float* __restrict__ W_out,
    const float* __restrict__ b_out, float* __restrict__ out) {
  const int lane = threadIdx.x & 63;
  const int l15 = lane & 15, l4 = lane >> 4;
  bf16x8 bfr[4][2];
  load_bfr(W_h, l15, l4, bfr);
  float scl[4], shf[4], wo[4];
#pragma unroll
  for (int nt = 0; nt < 4; ++nt) {
    scl[nt] = ss[l15 + 16 * nt];
    shf[nt] = ss[64 + l15 + 16 * nt];
    wo[nt] = W_out[l15 + 16 * nt];
  }
  const float bo = b_out[0];
  const int is64 = *flag;
  const long long* e64 = (const long long*)edges;
  const int* e32 = (const int*)edges;
  const int gwave = blockIdx.x * 4 + (threadIdx.x >> 6);
  const int nwaves = gridDim.x * 4;
  for (int chunk = gwave; chunk < N_CHUNKS; chunk += nwaves) {
    const int base = chunk * 64;
#pragma unroll
    for (int mt = 0; mt < 4; ++mt) {
      const int eidx = base + mt * 16 + l15;
      int s, d;
      if (is64) { s = (int)e64[eidx]; d = (int)e64[N_EDGES + eidx]; }
      else      { s = e32[eidx];      d = e32[N_EDGES + eidx]; }
      const uint4* As = (const uint4*)(A + (size_t)s * 128);
      const uint4* Ad = (const uint4*)(A + (size_t)d * 128 + 64);
      const bf16x8 a0 = frag_relu_add(As[l4], Ad[l4]);
      const bf16x8 a1 = frag_relu_add(As[4 + l4], Ad[4 + l4]);
      float t0 = 0.f, t1 = 0.f, t2 = 0.f, t3 = 0.f;
#pragma unroll
      for (int nt = 0; nt < 4; ++nt) {
        f32x4 cc = {0.f, 0.f, 0.f, 0.f};
        cc = __builtin_amdgcn_mfma_f32_16x16x32_bf16(a0, bfr[nt][0], cc, 0, 0, 0);
        cc = __builtin_amdgcn_mfma_f32_16x16x32_bf16(a1, bfr[nt][1], cc, 0, 0, 0);
        t0 += fmaxf(fmaf(cc[0], scl[nt], shf[nt]), 0.f) * wo[nt];
        t1 += fmaxf(fmaf(cc[1], scl[nt], shf[nt]), 0.f) * wo[nt];
        t2 += fmaxf(fmaf(cc[2], scl[nt], shf[nt]), 0.f) * wo[nt];
        t3 += fmaxf(fmaf(cc[3], scl[nt], shf[nt]), 0.f) * wo[nt];
      }
      const int ebase = base + mt * 16 + 4 * l4;
#pragma unroll
      for (int j = 0; j < 4; ++j) {
        float r = (j == 0) ? t0 : (j == 1) ? t1 : (j == 2) ? t2 : t3;
        r += __shfl_xor(r, 1, 64);
        r += __shfl_xor(r, 2, 64);
        r += __shfl_xor(r, 4, 64);
        r += __shfl_xor(r, 8, 64);
        if (l15 == 0) out[ebase + j] = r + bo;
      }
    }
  }
}

extern "C" void kernel_launch(void* const* d_in, const int* in_sizes, int n_in,
                              void* d_out, int out_size, void* d_ws, size_t ws_size,
                              hipStream_t stream) {
  const float* x     = (const float*)d_in[0];
  const void*  edges = d_in[1];
  const float* W_in  = (const float*)d_in[2];
  const float* b_in  = (const float*)d_in[3];
  const float* W_h   = (const float*)d_in[4];
  const float* gamma = (const float*)d_in[6];
  const float* beta  = (const float*)d_in[7];
  const float* W_out = (const float*)d_in[8];
  const float* b_out = (const float*)d_in[9];
  float* out = (float*)d_out;

  char* base = (char*)d_ws;
  __hip_bfloat16* A = (__hip_bfloat16*)base;
  const size_t offMeta = (size_t)N_NODES * 128 * sizeof(__hip_bfloat16);  // 25.6 MB
  float* stats = (float*)(base + offMeta);
  float* ss    = stats + 128;
  int*   flag  = (int*)(base + offMeta + 1024);
  __half* g = (__half*)(base + offMeta + 4096);
  const bool use_g = ws_size >= offMeta + 4096 + (size_t)N_EDGES * 64 * sizeof(__half);

  k1_mfma<<<782, 256, 0, stream>>>(x, W_in, b_in, (const unsigned*)edges, A, stats, flag);
  if (use_g) {
    k2_stats<true><<<976, 256, 0, stream>>>(A, edges, flag, W_h, stats, g);
    k3_finalize<<<1, 64, 0, stream>>>(stats, gamma, beta, ss);
    k4_stream<<<2048, 256, 0, stream>>>(g, ss, W_out, b_out, out);
  } else {
    k2_stats<false><<<976, 256, 0, stream>>>(A, edges, flag, W_h, stats, g);
    k3_finalize<<<1, 64, 0, stream>>>(stats, gamma, beta, ss);
    k4_gather<<<1024, 256, 0, stream>>>(A, edges, flag, W_h, ss, W_out, b_out, out);
  }
}